// Round 3
// baseline (429.750 us; speedup 1.0000x reference)
//
#include <hip/hip_runtime.h>
#include <hip/hip_bf16.h>
#include <math.h>

#define SEQ   2048
#define EMBED 2048
#define NHEAD 16
#define DHEAD 128
#define BATCH 2

#define NX   ((size_t)BATCH * SEQ * EMBED)   // 8388608
#define NW1  ((size_t)3 * EMBED * EMBED)     // 12582912
#define NB1  ((size_t)3 * EMBED)             // 6144
#define NW2  ((size_t)EMBED * EMBED)         // 4194304
#define NB2  ((size_t)EMBED)                 // 2048

typedef __bf16 bf16;
typedef __attribute__((__ext_vector_type__(8))) __bf16 bf16x8;
typedef __attribute__((__ext_vector_type__(4))) __bf16 bf16x4;
typedef __attribute__((__ext_vector_type__(4))) float f32x4;
typedef __attribute__((__ext_vector_type__(4))) unsigned int u32x4;

#define NEG_BIG (-1.0e30f)

__device__ __forceinline__ f32x4 mfma_16x16x32(bf16x8 a, bf16x8 b, f32x4 c) {
  return __builtin_amdgcn_mfma_f32_16x16x32_bf16(a, b, c, 0, 0, 0);
}

// async global->LDS, 16B per lane; dst is wave-uniform base, lane i lands at
// dst + i*16B (m97-verified pattern)
__device__ __forceinline__ void llds16(bf16* dst, const bf16* src) {
  __builtin_amdgcn_global_load_lds(
      (const __attribute__((address_space(1))) void*)src,
      (__attribute__((address_space(3))) void*)dst, 16, 0, 0);
}

// raw barrier: no vmcnt drain (unlike __syncthreads) -- keeps staging loads
// in flight across phases (T4). Memory clobbers pin LDS/global ops.
#define BAR()                                   \
  {                                             \
    asm volatile("" ::: "memory");              \
    __builtin_amdgcn_s_barrier();               \
    asm volatile("" ::: "memory");              \
  }

// ---------------------------------------------------------------------------
// Input normalization: detect fp32 vs bf16 storage, convert to bf16 ws.
// ---------------------------------------------------------------------------
__global__ void convert_inputs(const void* __restrict__ xin,
                               const void* __restrict__ w1in,
                               const void* __restrict__ b1in,
                               const void* __restrict__ w2in,
                               const void* __restrict__ b2in,
                               bf16* __restrict__ xb, bf16* __restrict__ w1b,
                               bf16* __restrict__ b1b, bf16* __restrict__ w2b,
                               bf16* __restrict__ b2b, int* __restrict__ flagp)
{
  __shared__ int sflag;
  if (threadIdx.x == 0) sflag = 0;
  __syncthreads();
  const unsigned short* xh = (const unsigned short*)xin;
  int huge = 0;
  for (int i = threadIdx.x; i < 2048; i += 256) {
    float f = __uint_as_float((unsigned int)xh[i] << 16);
    if (!(fabsf(f) <= 1e4f)) huge = 1;  // catches NaN/Inf too
  }
  if (huge) sflag = 1;
  __syncthreads();
  const int isf32 = sflag;
  if (blockIdx.x == 0 && threadIdx.x == 0) *flagp = isf32;

  const void* srcs[5] = {xin, w1in, b1in, w2in, b2in};
  bf16* dsts[5] = {xb, w1b, b1b, w2b, b2b};
  const size_t lens[5] = {NX, NW1, NB1, NW2, NB2};
  const size_t gid = (size_t)blockIdx.x * blockDim.x + threadIdx.x;
  const size_t gstride = (size_t)gridDim.x * blockDim.x;
  for (int sidx = 0; sidx < 5; ++sidx) {
    const size_t n8 = lens[sidx] >> 3;
    bf16* d = dsts[sidx];
    if (isf32) {
      const float* s = (const float*)srcs[sidx];
      for (size_t i = gid; i < n8; i += gstride) {
        const float* sp = s + i * 8;
        bf16x8 r;
#pragma unroll
        for (int j = 0; j < 8; ++j) r[j] = (bf16)sp[j];
        *(bf16x8*)(d + i * 8) = r;
      }
    } else {
      const u32x4* s = (const u32x4*)srcs[sidx];
      for (size_t i = gid; i < n8; i += gstride)
        *(u32x4*)(d + i * 8) = s[i];
    }
  }
}

// ---------------------------------------------------------------------------
// 8-phase 256x256 NT GEMM (m201 template port): C = A[M,K]*B[N,K]^T + bias
// BK=64; 512 threads = 8 waves (2M x 4N), 128x64 out/wave, acc[8][4] f32x4.
// LDS 128KB: [buf2][kh2][A|B][256 rows][32 k] bf16 -- K-half-major, 64B rows
//   -> ds_read_b128 fragment reads land at the 8-lane/slot bank FLOOR with
//      no swizzle, and global_load_lds dst stays linear (rule #21 trivial).
// Phase p=0..7 of iteration i (K-tiles 2i -> buf0 @p0-3, 2i+1 -> buf1 @p4-7);
// (ks,mh) = ((p>>1)&1, p&1). Per phase:
//   4x ds_read A-frags (+4x B-frags when mh==0; bfr reused at mh==1)
//   stage ONE half-tile (2x global_load_lds dwordx4):
//     p0:(2i+1)A.kh1 p1:(2i+1)B.kh1 p2:(2i+2)A.kh0 p3:(2i+2)B.kh0
//     p4:(2i+2)A.kh1 p5:(2i+2)B.kh1 p6:(2i+3)A.kh0 p7:(2i+3)B.kh0
//   (each target slot's last read completed >=1 barrier before the stage)
//   BAR ; setprio(1) ; 16 MFMA quadrant ; setprio(0)
//   vmcnt(4) at p3 and p7 ONLY (4 loads = 2 half-tiles in flight; every
//   half-tile lands >=5 phases before first read). Final iter p3: vmcnt(0).
// ---------------------------------------------------------------------------
template <int MODE>
__global__ __launch_bounds__(512, 2) void gemm8(
    const bf16* __restrict__ A, const bf16* __restrict__ B,
    const bf16* __restrict__ bias, int K,
    void* __restrict__ out0v, bf16* __restrict__ out1, bf16* __restrict__ out2,
    const int* __restrict__ flagp)
{
  __shared__ __align__(16) bf16 lds_[65536];  // 128 KiB
  constexpr int NBX = (MODE == 0) ? 24 : 8;   // N/256
  const int t = threadIdx.x;
  const int lane = t & 63, w = t >> 6;
  const int wm = w >> 2, wn = w & 3;          // 2M x 4N waves
  const int lr = lane & 15, lq = lane >> 4;
  // XCD-bijective swizzle (nwg % 8 == 0): each XCD gets a contiguous chunk
  const int nwg = NBX * 16;
  const int f = blockIdx.x;
  const int o = (f & 7) * (nwg >> 3) + (f >> 3);
  const int by = o / NBX, bx = o - by * NBX;
  const int m0 = by * 256, n0 = bx * 256;
  const int NT = K >> 6;                      // 32
  const int NI = NT >> 1;                     // 16

  // staging: half-tile = [256 rows][32 k] = 16KB = 2 block-wide calls;
  // call c: row = c*128 + (t>>2), 16B granule (t&3); LDS dst linear t*16B.
  const int srow = t >> 2, sg = t & 3;
  const bf16* aSrc = A + (size_t)(m0 + srow) * K + sg * 8;
  const bf16* bSrc = B + (size_t)(n0 + srow) * K + sg * 8;

#define HTSTAGE(isB, kt, kh)                                                 \
  {                                                                          \
    bf16* _d = lds_ + ((kt) & 1) * 32768 + (isB) * 16384 + (kh) * 8192 +     \
               w * 512;                                                      \
    const bf16* _s = ((isB) ? bSrc : aSrc) + (kt) * 64 + (kh) * 32;          \
    llds16(_d, _s);                                                          \
    llds16(_d + 4096, _s + (size_t)128 * K);                                 \
  }

  f32x4 acc[8][4];
#pragma unroll
  for (int i = 0; i < 8; ++i)
#pragma unroll
    for (int j = 0; j < 4; ++j) acc[i][j] = (f32x4){0.f, 0.f, 0.f, 0.f};

  // prologue: K0 fully + K1.kh0 (6 half-tiles, 12 loads); drain K0 (8 oldest)
  HTSTAGE(0, 0, 0); HTSTAGE(1, 0, 0); HTSTAGE(0, 0, 1); HTSTAGE(1, 0, 1);
  HTSTAGE(0, 1, 0); HTSTAGE(1, 1, 0);
  asm volatile("s_waitcnt vmcnt(4)" ::: "memory");
  BAR();

  bf16x8 bfr[4];
  for (int i = 0; i < NI; ++i) {
#pragma unroll
    for (int p = 0; p < 8; ++p) {
      const int mh = p & 1;
      const int rbase = (p >> 2) * 32768 + ((p >> 1) & 1) * 8192;
      bf16x8 af[4];
      const int arow = rbase + (wm * 128 + mh * 64 + lr) * 32 + lq * 8;
#pragma unroll
      for (int mi = 0; mi < 4; ++mi)
        af[mi] = *(const bf16x8*)(lds_ + arow + mi * 512);
      if (mh == 0) {
        const int brow = rbase + 16384 + (wn * 64 + lr) * 32 + lq * 8;
#pragma unroll
        for (int ni = 0; ni < 4; ++ni)
          bfr[ni] = *(const bf16x8*)(lds_ + brow + ni * 512);
      }
      const int skt = 2 * i + 1 + ((p + 2) >> 2);
      if (skt < NT) HTSTAGE(p & 1, skt, ((p >> 1) & 1) ^ 1);
      BAR();
      __builtin_amdgcn_s_setprio(1);
#pragma unroll
      for (int mi = 0; mi < 4; ++mi)
#pragma unroll
        for (int ni = 0; ni < 4; ++ni)
          acc[mh * 4 + mi][ni] =
              mfma_16x16x32(af[mi], bfr[ni], acc[mh * 4 + mi][ni]);
      __builtin_amdgcn_s_setprio(0);
      if (p == 3) {
        if (i == NI - 1) { asm volatile("s_waitcnt vmcnt(0)" ::: "memory"); }
        else             { asm volatile("s_waitcnt vmcnt(4)" ::: "memory"); }
      }
      if (p == 7) { asm volatile("s_waitcnt vmcnt(4)" ::: "memory"); }
      BAR();
    }
  }
#undef HTSTAGE

  // epilogue: C/D row(M) = wm*128 + MI*16 + lq*4 + reg, col(N) = wn*64 + ni*16 + lr
  if (MODE == 0) {
    const int which = n0 >> 11;
    const int bb = m0 >> 11;
    const int s0 = m0 & 2047;
    if (which == 2) {
      // V transposed: [BH, Dh, S]; 4 regs = 4 consecutive s -> 8B store
      bf16* dst = out2;
#pragma unroll
      for (int ni = 0; ni < 4; ++ni) {
        const int ng = n0 + wn * 64 + ni * 16 + lr;
        const int h = (ng >> 7) & 15;
        const int d = ng & 127;
        const float bv = (float)bias[ng];
        bf16* rowp =
            dst + ((size_t)(bb * NHEAD + h) * DHEAD + d) * SEQ + s0 + wm * 128;
#pragma unroll
        for (int MI = 0; MI < 8; ++MI) {
          bf16x4 pk;
#pragma unroll
          for (int reg = 0; reg < 4; ++reg)
            pk[reg] = (bf16)(acc[MI][ni][reg] + bv);
          *(bf16x4*)(rowp + MI * 16 + lq * 4) = pk;
        }
      }
    } else {
      bf16* dst = (which == 0) ? (bf16*)out0v : out1;
#pragma unroll
      for (int ni = 0; ni < 4; ++ni) {
        const int ng = n0 + wn * 64 + ni * 16 + lr;
        const int h = (ng >> 7) & 15;
        const int d = ng & 127;
        const float bv = (float)bias[ng];
        bf16* hb = dst + (size_t)(bb * NHEAD + h) * SEQ * DHEAD + d;
#pragma unroll
        for (int MI = 0; MI < 8; ++MI)
#pragma unroll
          for (int reg = 0; reg < 4; ++reg) {
            const int s = s0 + wm * 128 + MI * 16 + lq * 4 + reg;
            hb[(size_t)s * DHEAD] = (bf16)(acc[MI][ni][reg] + bv);
          }
      }
    }
  } else {
    const int isf32 = *flagp;
#pragma unroll
    for (int ni = 0; ni < 4; ++ni) {
      const int col = n0 + wn * 64 + ni * 16 + lr;
      const float bv = (float)bias[col];
#pragma unroll
      for (int MI = 0; MI < 8; ++MI)
#pragma unroll
        for (int reg = 0; reg < 4; ++reg) {
          const int row = m0 + wm * 128 + MI * 16 + lq * 4 + reg;
          const float v = acc[MI][ni][reg] + bv;
          const size_t idx = (size_t)row * EMBED + col;
          if (isf32) ((float*)out0v)[idx] = v;
          else       ((bf16*)out0v)[idx] = (bf16)v;
        }
    }
  }
}

// ---------------------------------------------------------------------------
// Causal flash attention, pair-balanced: block (bh, p) handles q-tiles
// {p, 31-p} (64 rows each) over the shared K range kt=0..31-p.
// Swapped-operand form: S^T = mfma(K,Q); lane owns one q-row; P via
// XOR-swizzled packed ds_write_b64; PV computes O^T = V^T * P^T.
// ---------------------------------------------------------------------------
__device__ __forceinline__ void qk_softmax_tile(
    const bf16* __restrict__ sK, bf16* __restrict__ sP, const bf16x8* aq,
    float& m_i, float& l_i, f32x4* oacc, int kt, int qt,
    int w, int lr, int lq, int sPofs)
{
  const float scale = 0.08838834764831845f;  // 1/sqrt(128)
  f32x4 tacc[4];
#pragma unroll
  for (int ni = 0; ni < 4; ++ni) tacc[ni] = (f32x4){0.f, 0.f, 0.f, 0.f};
#pragma unroll
  for (int ks = 0; ks < 4; ++ks)
#pragma unroll
    for (int ni = 0; ni < 4; ++ni) {
      bf16x8 bk = *(const bf16x8*)(sK + (ni * 16 + lr) * 136 + ks * 32 + lq * 8);
      tacc[ni] = mfma_16x16x32(bk, aq[ks], tacc[ni]);
    }
  float pp[4][4];
  const int qg = qt * 64 + w * 16 + lr;
#pragma unroll
  for (int ni = 0; ni < 4; ++ni)
#pragma unroll
    for (int reg = 0; reg < 4; ++reg) {
      float sv = tacc[ni][reg] * scale;
      if (kt == qt) {
        const int kg = kt * 64 + ni * 16 + lq * 4 + reg;
        if (kg > qg) sv = NEG_BIG;
      }
      pp[ni][reg] = sv;
    }
  float mx;
  {
    float a0 = fmaxf(fmaxf(pp[0][0], pp[0][1]), fmaxf(pp[0][2], pp[0][3]));
    float a1 = fmaxf(fmaxf(pp[1][0], pp[1][1]), fmaxf(pp[1][2], pp[1][3]));
    float a2 = fmaxf(fmaxf(pp[2][0], pp[2][1]), fmaxf(pp[2][2], pp[2][3]));
    float a3 = fmaxf(fmaxf(pp[3][0], pp[3][1]), fmaxf(pp[3][2], pp[3][3]));
    mx = fmaxf(fmaxf(a0, a1), fmaxf(a2, a3));
  }
  mx = fmaxf(mx, __shfl_xor(mx, 16, 64));
  mx = fmaxf(mx, __shfl_xor(mx, 32, 64));
  const float mnew = fmaxf(m_i, mx);
  const float alpha = __expf(m_i - mnew);
  float ls = 0.f;
#pragma unroll
  for (int ni = 0; ni < 4; ++ni) {
    float s0 = __expf(pp[ni][0] - mnew);
    float s1 = __expf(pp[ni][1] - mnew);
    float s2 = __expf(pp[ni][2] - mnew);
    float s3 = __expf(pp[ni][3] - mnew);
    pp[ni][0] = s0; pp[ni][1] = s1; pp[ni][2] = s2; pp[ni][3] = s3;
    ls += (s0 + s1) + (s2 + s3);
  }
  ls += __shfl_xor(ls, 16, 64);
  ls += __shfl_xor(ls, 32, 64);
  l_i = l_i * alpha + ls;
  m_i = mnew;
#pragma unroll
  for (int dt = 0; dt < 8; ++dt) oacc[dt] *= alpha;
  bf16* rowp = sP + (sPofs + w * 16 + lr) * 64;
  const int swz = lr & 7;
#pragma unroll
  for (int ni = 0; ni < 4; ++ni) {
    bf16x4 pk;
#pragma unroll
    for (int reg = 0; reg < 4; ++reg) pk[reg] = (bf16)pp[ni][reg];
    const int col = ni * 16 + lq * 4;
    const int scol = (((col >> 3) ^ swz) << 3) | (col & 7);
    *(bf16x4*)(rowp + scol) = pk;
  }
}

__device__ __forceinline__ void pv_tile(const bf16* __restrict__ sP,
                                        const bf16* __restrict__ sV,
                                        f32x4* oacc, int w, int lr, int lq,
                                        int sPofs)
{
  const bf16* rowp = sP + (sPofs + w * 16 + lr) * 64;
  const int swz = lr & 7;
#pragma unroll
  for (int ks2 = 0; ks2 < 2; ++ks2) {
    const int chunk = ks2 * 4 + lq;
    bf16x8 bp = *(const bf16x8*)(rowp + ((chunk ^ swz) << 3));
#pragma unroll
    for (int dt = 0; dt < 8; ++dt) {
      bf16x8 av =
          *(const bf16x8*)(sV + (dt * 16 + lr) * 72 + ks2 * 32 + lq * 8);
      oacc[dt] = mfma_16x16x32(av, bp, oacc[dt]);
    }
  }
}

__global__ __launch_bounds__(256, 2) void attn_fwd(
    const bf16* __restrict__ qb, const bf16* __restrict__ kb,
    const bf16* __restrict__ vt, bf16* __restrict__ aout)
{
  __shared__ bf16 sK[64 * 136];    // [k][d], +8 pad
  __shared__ bf16 sV[128 * 72];    // [d][k], +8 pad
  __shared__ bf16 sP[128 * 64];    // [q][k] XOR-swizzled
  const int t = threadIdx.x;
  const int lane = t & 63, w = t >> 6;
  const int lr = lane & 15, lq = lane >> 4;
  const int p  = blockIdx.x & 15;
  const int bh = blockIdx.x >> 4;
  const int bb = bh >> 4, h = bh & 15;
  const int qlo = p, qhi = 31 - p;

  bf16x8 aqL[4], aqH[4];
  {
    const bf16* qpL =
        qb + ((size_t)bh * SEQ + qlo * 64 + w * 16 + lr) * DHEAD + lq * 8;
    const bf16* qpH =
        qb + ((size_t)bh * SEQ + qhi * 64 + w * 16 + lr) * DHEAD + lq * 8;
#pragma unroll
    for (int ks = 0; ks < 4; ++ks) {
      aqL[ks] = *(const bf16x8*)(qpL + ks * 32);
      aqH[ks] = *(const bf16x8*)(qpH + ks * 32);
    }
  }

  f32x4 oL[8], oH[8];
#pragma unroll
  for (int i = 0; i < 8; ++i) {
    oL[i] = (f32x4){0.f, 0.f, 0.f, 0.f};
    oH[i] = (f32x4){0.f, 0.f, 0.f, 0.f};
  }
  float mL = NEG_BIG, mH = NEG_BIG;
  float lL = 0.f, lH = 0.f;

  bf16x8 rk[4], rv[4];
  const int kr_ = t >> 4, kd_ = t & 15;
  const int vr_ = t >> 3, vk_ = t & 7;
#define FETCH(ktv)                                                          \
  {                                                                         \
    const int _kt = (ktv);                                                  \
    _Pragma("unroll") for (int i = 0; i < 4; ++i) {                         \
      rk[i] = *(const bf16x8*)(kb + ((size_t)bh * SEQ + _kt * 64 +          \
                                     (i * 16 + kr_)) * DHEAD + kd_ * 8);    \
      rv[i] = *(const bf16x8*)(vt + ((size_t)bh * DHEAD + (i * 32 + vr_)) * \
                                     SEQ + _kt * 64 + vk_ * 8);             \
    }                                                                       \
  }
#define COMMIT()                                                            \
  {                                                                         \
    _Pragma("unroll") for (int i = 0; i < 4; ++i) {                         \
      *(bf16x8*)(sK + (i * 16 + kr_) * 136 + kd_ * 8) = rk[i];              \
      *(bf16x8*)(sV + (i * 32 + vr_) * 72 + vk_ * 8) = rv[i];               \
    }                                                                       \
  }

  FETCH(0);
  COMMIT();
  __syncthreads();

  for (int kt = 0; kt <= qhi; ++kt) {
    if (kt < qhi) FETCH(kt + 1);
    const bool doLo = (kt <= qlo);

    qk_softmax_tile(sK, sP, aqH, mH, lH, oH, kt, qhi, w, lr, lq, 64);
    if (doLo) qk_softmax_tile(sK, sP, aqL, mL, lL, oL, kt, qlo, w, lr, lq, 0);
    asm volatile("s_waitcnt lgkmcnt(0)" ::: "memory");
    pv_tile(sP, sV, oH, w, lr, lq, 64);
    if (doLo) pv_tile(sP, sV, oL, w, lr, lq, 0);

    __syncthreads();
    if (kt < qhi) {
      COMMIT();
      __syncthreads();
    }
  }

#pragma unroll
  for (int side = 0; side < 2; ++side) {
    const f32x4* oacc = side ? oH : oL;
    const float linv = 1.0f / (side ? lH : lL);
    const int qt = side ? qhi : qlo;
    const int qg = qt * 64 + w * 16 + lr;
    bf16* outp = aout + ((size_t)bb * SEQ + qg) * EMBED + h * 128 + lq * 4;
#pragma unroll
    for (int dt = 0; dt < 8; ++dt) {
      bf16x4 pk;
#pragma unroll
      for (int reg = 0; reg < 4; ++reg)
        pk[reg] = (bf16)(oacc[dt][reg] * linv);
      *(bf16x4*)(outp + dt * 16) = pk;
    }
  }
#undef FETCH
#undef COMMIT
}

extern "C" void kernel_launch(void* const* d_in, const int* in_sizes, int n_in,
                              void* d_out, int out_size, void* d_ws, size_t ws_size,
                              hipStream_t stream) {
  const void* x    = d_in[0];
  const void* Wqkv = d_in[1];
  const void* bqkv = d_in[2];
  const void* Wout = d_in[3];
  const void* bout = d_in[4];

  int* flagp = (int*)d_ws;
  bf16* base = (bf16*)((char*)d_ws + 256);
  bf16* xb   = base;
  bf16* w1b  = xb + NX;
  bf16* b1b  = w1b + NW1;
  bf16* w2b  = b1b + NB1;
  bf16* b2b  = w2b + NW2;
  bf16* qb   = b2b + NB2;
  bf16* kb   = qb + NX;
  bf16* vt   = kb + NX;
  bf16* aout = vt + NX;

  convert_inputs<<<dim3(1024), dim3(256), 0, stream>>>(
      x, Wqkv, bqkv, Wout, bout, xb, w1b, b1b, w2b, b2b, flagp);
  // QKV projection: M=4096, N=6144, K=2048 -> 384 blocks (256x256 tiles)
  gemm8<0><<<dim3(384), dim3(512), 0, stream>>>(
      xb, w1b, b1b, EMBED, (void*)qb, kb, vt, flagp);
  // attention: 32 bh * 16 balanced pairs
  attn_fwd<<<dim3(512), dim3(256), 0, stream>>>(qb, kb, vt, aout);
  // out projection: M=4096, N=2048, K=2048 -> 128 blocks
  gemm8<1><<<dim3(128), dim3(512), 0, stream>>>(
      aout, w2b, b2b, EMBED, d_out, nullptr, nullptr, flagp);
}

// Round 4
// 394.987 us; speedup vs baseline: 1.0880x; 1.0880x over previous
//
#include <hip/hip_runtime.h>
#include <hip/hip_bf16.h>
#include <math.h>

#define SEQ   2048
#define EMBED 2048
#define NHEAD 16
#define DHEAD 128
#define BATCH 2

#define NX   ((size_t)BATCH * SEQ * EMBED)   // 8388608
#define NW1  ((size_t)3 * EMBED * EMBED)     // 12582912
#define NB1  ((size_t)3 * EMBED)             // 6144
#define NW2  ((size_t)EMBED * EMBED)         // 4194304
#define NB2  ((size_t)EMBED)                 // 2048

typedef __bf16 bf16;
typedef __attribute__((__ext_vector_type__(8))) __bf16 bf16x8;
typedef __attribute__((__ext_vector_type__(4))) __bf16 bf16x4;
typedef __attribute__((__ext_vector_type__(4))) float f32x4;
typedef __attribute__((__ext_vector_type__(4))) unsigned int u32x4;

#define NEG_BIG (-1.0e30f)

__device__ __forceinline__ f32x4 mfma_16x16x32(bf16x8 a, bf16x8 b, f32x4 c) {
  return __builtin_amdgcn_mfma_f32_16x16x32_bf16(a, b, c, 0, 0, 0);
}

// async global->LDS, 16B per lane; dst is wave-uniform base, lane i lands at
// dst + i*16B (m97-verified pattern)
__device__ __forceinline__ void llds16(bf16* dst, const bf16* src) {
  __builtin_amdgcn_global_load_lds(
      (const __attribute__((address_space(1))) void*)src,
      (__attribute__((address_space(3))) void*)dst, 16, 0, 0);
}

// raw barrier emitted as opaque asm: the compiler's memory legalizer cannot
// attach an s_waitcnt vmcnt(0) drain to it (T4 insurance). "memory" clobber
// still pins all LDS/global ops on either side.
#define BARRAW() asm volatile("s_barrier" ::: "memory")

// ---------------------------------------------------------------------------
// Input normalization: detect fp32 vs bf16 storage, convert to bf16 ws.
// ---------------------------------------------------------------------------
__global__ void convert_inputs(const void* __restrict__ xin,
                               const void* __restrict__ w1in,
                               const void* __restrict__ b1in,
                               const void* __restrict__ w2in,
                               const void* __restrict__ b2in,
                               bf16* __restrict__ xb, bf16* __restrict__ w1b,
                               bf16* __restrict__ b1b, bf16* __restrict__ w2b,
                               bf16* __restrict__ b2b, int* __restrict__ flagp)
{
  __shared__ int sflag;
  if (threadIdx.x == 0) sflag = 0;
  __syncthreads();
  const unsigned short* xh = (const unsigned short*)xin;
  int huge = 0;
  for (int i = threadIdx.x; i < 2048; i += 256) {
    float f = __uint_as_float((unsigned int)xh[i] << 16);
    if (!(fabsf(f) <= 1e4f)) huge = 1;  // catches NaN/Inf too
  }
  if (huge) sflag = 1;
  __syncthreads();
  const int isf32 = sflag;
  if (blockIdx.x == 0 && threadIdx.x == 0) *flagp = isf32;

  const void* srcs[5] = {xin, w1in, b1in, w2in, b2in};
  bf16* dsts[5] = {xb, w1b, b1b, w2b, b2b};
  const size_t lens[5] = {NX, NW1, NB1, NW2, NB2};
  const size_t gid = (size_t)blockIdx.x * blockDim.x + threadIdx.x;
  const size_t gstride = (size_t)gridDim.x * blockDim.x;
  for (int sidx = 0; sidx < 5; ++sidx) {
    const size_t n8 = lens[sidx] >> 3;
    bf16* d = dsts[sidx];
    if (isf32) {
      const float* s = (const float*)srcs[sidx];
      for (size_t i = gid; i < n8; i += gstride) {
        const float* sp = s + i * 8;
        bf16x8 r;
#pragma unroll
        for (int j = 0; j < 8; ++j) r[j] = (bf16)sp[j];
        *(bf16x8*)(d + i * 8) = r;
      }
    } else {
      const u32x4* s = (const u32x4*)srcs[sidx];
      for (size_t i = gid; i < n8; i += gstride)
        *(u32x4*)(d + i * 8) = s[i];
    }
  }
}

// ---------------------------------------------------------------------------
// 4-phase pipelined NT GEMM: C[M,N] = A[M,K]*B[N,K]^T + bias[N]
// BM=128, BN=256, BK=64; 512 thr = 8 waves (2M x 4N), 64x64 out/wave.
// LDS 96KB: [buf2]{ A:[ks2][128][32] ; B:[ks2][256][32] } bf16, 64B rows.
//   Swizzle (m201 st_16x32 equivalent): granule-bit1 ^= row-bit3, applied on
//   BOTH the stage SOURCE address and the ds_read address (rule #21); LDS
//   destinations stay linear for global_load_lds.
// Iter i covers K-tiles 2i (buf0, phases 0-1) and 2i+1 (buf1, phases 2-3);
// phase p: ks = p&1. Per phase: 8 ds_read_b128 (4 A + 4 B frags), stage ONE
// ks-half-set (3 llds16/wave):
//   p0:(2i+1).ks1  p1:(2i+2).ks0  p2:(2i+2).ks1  p3:(2i+3).ks0
// (each target slot's last read completed >=1 barrier before the stage;
// stage/read regions within a phase are disjoint -- verified per-region).
// Waits: vmcnt(3) at end-p1 and end-p3 ONLY (3 calls = 1 half-set stays in
// flight; every half-set lands >=1 barrier before its first read).
// Prologue: stage (0)ks0,(0)ks1,(1)ks0; vmcnt(6); extra vmcnt(6) at i0/p0.
// Tail: i=NI-1 stages only p0; end-p1 -> vmcnt(0); end-p3 wait skipped.
// Grids are EXACT: MODE0 768 blocks = 3 full rounds; MODE1 256 = 1 round.
// ---------------------------------------------------------------------------
template <int MODE>
__global__ __launch_bounds__(512, 1) void gemmE(
    const bf16* __restrict__ A, const bf16* __restrict__ B,
    const bf16* __restrict__ bias, int K,
    void* __restrict__ out0v, bf16* __restrict__ out1, bf16* __restrict__ out2,
    const int* __restrict__ flagp)
{
  __shared__ __align__(16) bf16 lds_[49152];  // 96 KiB
  constexpr int NTX = (MODE == 0) ? 24 : 8;   // N / 256
  const int t = threadIdx.x;
  const int lane = t & 63, w = t >> 6;
  const int wm = w >> 2, wn = w & 3;          // 2M x 4N waves
  const int lr = lane & 15, lq = lane >> 4;
  // XCD-bijective swizzle (nwg % 8 == 0); within an XCD chunk, by varies
  // fastest -> the 1MB B-panel stays L2-resident while A-strips stream.
  const int nwg = 32 * NTX;
  const int f = blockIdx.x;
  const int o = (f & 7) * (nwg >> 3) + (f >> 3);
  const int by = o & 31, bx = o >> 5;
  const int m0 = by << 7, n0 = bx << 8;
  const int NT = K >> 6;                      // 32 K-tiles
  const int NI = NT >> 1;                     // 16 iterations

  // staging thread map: row = t>>2 (of 128 for A / per-128-half for B),
  // phys granule = t&3; logical source granule = phys ^ ((row>>3)&1)<<1.
  const int srow = t >> 2;
  const int sg8 = (((t & 3) ^ (((t >> 5) & 1) << 1))) << 3;

#define STAGE3(kt_, ks_)                                                     \
  {                                                                          \
    const int _kt = (kt_), _ks = (ks_);                                      \
    if (_kt < NT) {                                                          \
      const int _bb = (_kt & 1) * 24576;                                     \
      const int _kc = (_kt << 6) + _ks * 32;                                 \
      llds16(lds_ + _bb + _ks * 4096 + (w << 9),                             \
             A + (size_t)(m0 + srow) * K + _kc + sg8);                       \
      llds16(lds_ + _bb + 8192 + _ks * 8192 + (w << 9),                      \
             B + (size_t)(n0 + srow) * K + _kc + sg8);                       \
      llds16(lds_ + _bb + 8192 + _ks * 8192 + 4096 + (w << 9),               \
             B + (size_t)(n0 + 128 + srow) * K + _kc + sg8);                 \
    }                                                                        \
  }

  f32x4 acc[4][4];
#pragma unroll
  for (int i = 0; i < 4; ++i)
#pragma unroll
    for (int j = 0; j < 4; ++j) acc[i][j] = (f32x4){0.f, 0.f, 0.f, 0.f};

  // ds_read granule with the same XOR (row-bit3 of base+lr = lr>>3, since
  // fragment base rows are multiples of 16)
  const int rg8 = ((lq ^ (((lr >> 3) & 1) << 1))) << 3;
  const int arow = (wm * 64 + lr) * 32 + rg8;
  const int brow = (wn * 64 + lr) * 32 + rg8;

  // prologue
  STAGE3(0, 0);
  STAGE3(0, 1);
  STAGE3(1, 0);
  asm volatile("s_waitcnt vmcnt(6)" ::: "memory");
  BARRAW();

  for (int i = 0; i < NI; ++i) {
    const int k2 = i << 1;
#pragma unroll
    for (int p = 0; p < 4; ++p) {
      const int ks = p & 1;
      const int bufb = (p >> 1) * 24576;
      bf16x8 af[4], bfv[4];
      const int ab = bufb + ks * 4096 + arow;
      const int bb = bufb + 8192 + ks * 8192 + brow;
#pragma unroll
      for (int mi = 0; mi < 4; ++mi)
        af[mi] = *(const bf16x8*)(lds_ + ab + mi * 512);
#pragma unroll
      for (int ni = 0; ni < 4; ++ni)
        bfv[ni] = *(const bf16x8*)(lds_ + bb + ni * 512);
      // stage ring
      if (p == 0)      STAGE3(k2 + 1, 1)
      else if (p == 1) STAGE3(k2 + 2, 0)
      else if (p == 2) STAGE3(k2 + 2, 1)
      else             STAGE3(k2 + 3, 0)
      BARRAW();
      __builtin_amdgcn_s_setprio(1);
#pragma unroll
      for (int mi = 0; mi < 4; ++mi)
#pragma unroll
        for (int ni = 0; ni < 4; ++ni)
          acc[mi][ni] = mfma_16x16x32(af[mi], bfv[ni], acc[mi][ni]);
      __builtin_amdgcn_s_setprio(0);
      if (i == 0 && p == 0) {
        asm volatile("s_waitcnt vmcnt(6)" ::: "memory");
      }
      if (p == 1) {
        if (i == NI - 1) { asm volatile("s_waitcnt vmcnt(0)" ::: "memory"); }
        else             { asm volatile("s_waitcnt vmcnt(3)" ::: "memory"); }
      }
      if (p == 3 && i < NI - 1) {
        asm volatile("s_waitcnt vmcnt(3)" ::: "memory");
      }
      BARRAW();
    }
  }
#undef STAGE3

  // epilogue: C/D row(M) = wm*64 + mi*16 + lq*4 + reg, col(N) = wn*64+ni*16+lr
  if (MODE == 0) {
    const int which = n0 >> 11;
    const int bbid = m0 >> 11;
    const int s0 = m0 & 2047;
    if (which == 2) {
      // V transposed: [BH, Dh, S]; 4 regs = 4 consecutive s -> 8B store
      bf16* dst = out2;
#pragma unroll
      for (int ni = 0; ni < 4; ++ni) {
        const int ng = n0 + wn * 64 + ni * 16 + lr;
        const int h = (ng >> 7) & 15;
        const int d = ng & 127;
        const float bv = (float)bias[ng];
        bf16* rowp =
            dst + ((size_t)(bbid * NHEAD + h) * DHEAD + d) * SEQ + s0 + wm * 64;
#pragma unroll
        for (int mi = 0; mi < 4; ++mi) {
          bf16x4 pk;
#pragma unroll
          for (int reg = 0; reg < 4; ++reg)
            pk[reg] = (bf16)(acc[mi][ni][reg] + bv);
          *(bf16x4*)(rowp + mi * 16 + lq * 4) = pk;
        }
      }
    } else {
      bf16* dst = (which == 0) ? (bf16*)out0v : out1;
#pragma unroll
      for (int ni = 0; ni < 4; ++ni) {
        const int ng = n0 + wn * 64 + ni * 16 + lr;
        const int h = (ng >> 7) & 15;
        const int d = ng & 127;
        const float bv = (float)bias[ng];
        bf16* hb = dst + (size_t)(bbid * NHEAD + h) * SEQ * DHEAD + d;
#pragma unroll
        for (int mi = 0; mi < 4; ++mi)
#pragma unroll
          for (int reg = 0; reg < 4; ++reg) {
            const int s = s0 + wm * 64 + mi * 16 + lq * 4 + reg;
            hb[(size_t)s * DHEAD] = (bf16)(acc[mi][ni][reg] + bv);
          }
      }
    }
  } else {
    const int isf32 = *flagp;
#pragma unroll
    for (int ni = 0; ni < 4; ++ni) {
      const int col = n0 + wn * 64 + ni * 16 + lr;
      const float bv = (float)bias[col];
#pragma unroll
      for (int mi = 0; mi < 4; ++mi)
#pragma unroll
        for (int reg = 0; reg < 4; ++reg) {
          const int row = m0 + wm * 64 + mi * 16 + lq * 4 + reg;
          const float v = acc[mi][ni][reg] + bv;
          const size_t idx = (size_t)row * EMBED + col;
          if (isf32) ((float*)out0v)[idx] = v;
          else       ((bf16*)out0v)[idx] = (bf16)v;
        }
    }
  }
}

// ---------------------------------------------------------------------------
// Causal flash attention, pair-balanced: block (bh, p) handles q-tiles
// {p, 31-p} (64 rows each) over the shared K range kt=0..31-p.
// Swapped-operand form: S^T = mfma(K,Q); lane owns one q-row; P via
// XOR-swizzled packed ds_write_b64; PV computes O^T = V^T * P^T.
// ---------------------------------------------------------------------------
__device__ __forceinline__ void qk_softmax_tile(
    const bf16* __restrict__ sK, bf16* __restrict__ sP, const bf16x8* aq,
    float& m_i, float& l_i, f32x4* oacc, int kt, int qt,
    int w, int lr, int lq, int sPofs)
{
  const float scale = 0.08838834764831845f;  // 1/sqrt(128)
  f32x4 tacc[4];
#pragma unroll
  for (int ni = 0; ni < 4; ++ni) tacc[ni] = (f32x4){0.f, 0.f, 0.f, 0.f};
#pragma unroll
  for (int ks = 0; ks < 4; ++ks)
#pragma unroll
    for (int ni = 0; ni < 4; ++ni) {
      bf16x8 bk = *(const bf16x8*)(sK + (ni * 16 + lr) * 136 + ks * 32 + lq * 8);
      tacc[ni] = mfma_16x16x32(bk, aq[ks], tacc[ni]);
    }
  float pp[4][4];
  const int qg = qt * 64 + w * 16 + lr;
#pragma unroll
  for (int ni = 0; ni < 4; ++ni)
#pragma unroll
    for (int reg = 0; reg < 4; ++reg) {
      float sv = tacc[ni][reg] * scale;
      if (kt == qt) {
        const int kg = kt * 64 + ni * 16 + lq * 4 + reg;
        if (kg > qg) sv = NEG_BIG;
      }
      pp[ni][reg] = sv;
    }
  float mx;
  {
    float a0 = fmaxf(fmaxf(pp[0][0], pp[0][1]), fmaxf(pp[0][2], pp[0][3]));
    float a1 = fmaxf(fmaxf(pp[1][0], pp[1][1]), fmaxf(pp[1][2], pp[1][3]));
    float a2 = fmaxf(fmaxf(pp[2][0], pp[2][1]), fmaxf(pp[2][2], pp[2][3]));
    float a3 = fmaxf(fmaxf(pp[3][0], pp[3][1]), fmaxf(pp[3][2], pp[3][3]));
    mx = fmaxf(fmaxf(a0, a1), fmaxf(a2, a3));
  }
  mx = fmaxf(mx, __shfl_xor(mx, 16, 64));
  mx = fmaxf(mx, __shfl_xor(mx, 32, 64));
  const float mnew = fmaxf(m_i, mx);
  const float alpha = __expf(m_i - mnew);
  float ls = 0.f;
#pragma unroll
  for (int ni = 0; ni < 4; ++ni) {
    float s0 = __expf(pp[ni][0] - mnew);
    float s1 = __expf(pp[ni][1] - mnew);
    float s2 = __expf(pp[ni][2] - mnew);
    float s3 = __expf(pp[ni][3] - mnew);
    pp[ni][0] = s0; pp[ni][1] = s1; pp[ni][2] = s2; pp[ni][3] = s3;
    ls += (s0 + s1) + (s2 + s3);
  }
  ls += __shfl_xor(ls, 16, 64);
  ls += __shfl_xor(ls, 32, 64);
  l_i = l_i * alpha + ls;
  m_i = mnew;
#pragma unroll
  for (int dt = 0; dt < 8; ++dt) oacc[dt] *= alpha;
  bf16* rowp = sP + (sPofs + w * 16 + lr) * 64;
  const int swz = lr & 7;
#pragma unroll
  for (int ni = 0; ni < 4; ++ni) {
    bf16x4 pk;
#pragma unroll
    for (int reg = 0; reg < 4; ++reg) pk[reg] = (bf16)pp[ni][reg];
    const int col = ni * 16 + lq * 4;
    const int scol = (((col >> 3) ^ swz) << 3) | (col & 7);
    *(bf16x4*)(rowp + scol) = pk;
  }
}

__device__ __forceinline__ void pv_tile(const bf16* __restrict__ sP,
                                        const bf16* __restrict__ sV,
                                        f32x4* oacc, int w, int lr, int lq,
                                        int sPofs)
{
  const bf16* rowp = sP + (sPofs + w * 16 + lr) * 64;
  const int swz = lr & 7;
#pragma unroll
  for (int ks2 = 0; ks2 < 2; ++ks2) {
    const int chunk = ks2 * 4 + lq;
    bf16x8 bp = *(const bf16x8*)(rowp + ((chunk ^ swz) << 3));
#pragma unroll
    for (int dt = 0; dt < 8; ++dt) {
      bf16x8 av =
          *(const bf16x8*)(sV + (dt * 16 + lr) * 72 + ks2 * 32 + lq * 8);
      oacc[dt] = mfma_16x16x32(av, bp, oacc[dt]);
    }
  }
}

__global__ __launch_bounds__(256, 2) void attn_fwd(
    const bf16* __restrict__ qb, const bf16* __restrict__ kb,
    const bf16* __restrict__ vt, bf16* __restrict__ aout)
{
  __shared__ bf16 sK[64 * 136];    // [k][d], +8 pad
  __shared__ bf16 sV[128 * 72];    // [d][k], +8 pad
  __shared__ bf16 sP[128 * 64];    // [q][k] XOR-swizzled
  const int t = threadIdx.x;
  const int lane = t & 63, w = t >> 6;
  const int lr = lane & 15, lq = lane >> 4;
  const int p  = blockIdx.x & 15;
  const int bh = blockIdx.x >> 4;
  const int bb = bh >> 4, h = bh & 15;
  const int qlo = p, qhi = 31 - p;

  bf16x8 aqL[4], aqH[4];
  {
    const bf16* qpL =
        qb + ((size_t)bh * SEQ + qlo * 64 + w * 16 + lr) * DHEAD + lq * 8;
    const bf16* qpH =
        qb + ((size_t)bh * SEQ + qhi * 64 + w * 16 + lr) * DHEAD + lq * 8;
#pragma unroll
    for (int ks = 0; ks < 4; ++ks) {
      aqL[ks] = *(const bf16x8*)(qpL + ks * 32);
      aqH[ks] = *(const bf16x8*)(qpH + ks * 32);
    }
  }

  f32x4 oL[8], oH[8];
#pragma unroll
  for (int i = 0; i < 8; ++i) {
    oL[i] = (f32x4){0.f, 0.f, 0.f, 0.f};
    oH[i] = (f32x4){0.f, 0.f, 0.f, 0.f};
  }
  float mL = NEG_BIG, mH = NEG_BIG;
  float lL = 0.f, lH = 0.f;

  bf16x8 rk[4], rv[4];
  const int kr_ = t >> 4, kd_ = t & 15;
  const int vr_ = t >> 3, vk_ = t & 7;
#define FETCH(ktv)                                                          \
  {                                                                         \
    const int _kt = (ktv);                                                  \
    _Pragma("unroll") for (int i = 0; i < 4; ++i) {                         \
      rk[i] = *(const bf16x8*)(kb + ((size_t)bh * SEQ + _kt * 64 +          \
                                     (i * 16 + kr_)) * DHEAD + kd_ * 8);    \
      rv[i] = *(const bf16x8*)(vt + ((size_t)bh * DHEAD + (i * 32 + vr_)) * \
                                     SEQ + _kt * 64 + vk_ * 8);             \
    }                                                                       \
  }
#define COMMIT()                                                            \
  {                                                                         \
    _Pragma("unroll") for (int i = 0; i < 4; ++i) {                         \
      *(bf16x8*)(sK + (i * 16 + kr_) * 136 + kd_ * 8) = rk[i];              \
      *(bf16x8*)(sV + (i * 32 + vr_) * 72 + vk_ * 8) = rv[i];               \
    }                                                                       \
  }

  FETCH(0);
  COMMIT();
  __syncthreads();

  for (int kt = 0; kt <= qhi; ++kt) {
    if (kt < qhi) FETCH(kt + 1);
    const bool doLo = (kt <= qlo);

    qk_softmax_tile(sK, sP, aqH, mH, lH, oH, kt, qhi, w, lr, lq, 64);
    if (doLo) qk_softmax_tile(sK, sP, aqL, mL, lL, oL, kt, qlo, w, lr, lq, 0);
    asm volatile("s_waitcnt lgkmcnt(0)" ::: "memory");
    pv_tile(sP, sV, oH, w, lr, lq, 64);
    if (doLo) pv_tile(sP, sV, oL, w, lr, lq, 0);

    __syncthreads();
    if (kt < qhi) {
      COMMIT();
      __syncthreads();
    }
  }

#pragma unroll
  for (int side = 0; side < 2; ++side) {
    const f32x4* oacc = side ? oH : oL;
    const float linv = 1.0f / (side ? lH : lL);
    const int qt = side ? qhi : qlo;
    const int qg = qt * 64 + w * 16 + lr;
    bf16* outp = aout + ((size_t)bb * SEQ + qg) * EMBED + h * 128 + lq * 4;
#pragma unroll
    for (int dt = 0; dt < 8; ++dt) {
      bf16x4 pk;
#pragma unroll
      for (int reg = 0; reg < 4; ++reg)
        pk[reg] = (bf16)(oacc[dt][reg] * linv);
      *(bf16x4*)(outp + dt * 16) = pk;
    }
  }
#undef FETCH
#undef COMMIT
}

extern "C" void kernel_launch(void* const* d_in, const int* in_sizes, int n_in,
                              void* d_out, int out_size, void* d_ws, size_t ws_size,
                              hipStream_t stream) {
  const void* x    = d_in[0];
  const void* Wqkv = d_in[1];
  const void* bqkv = d_in[2];
  const void* Wout = d_in[3];
  const void* bout = d_in[4];

  int* flagp = (int*)d_ws;
  bf16* base = (bf16*)((char*)d_ws + 256);
  bf16* xb   = base;
  bf16* w1b  = xb + NX;
  bf16* b1b  = w1b + NW1;
  bf16* w2b  = b1b + NB1;
  bf16* b2b  = w2b + NW2;
  bf16* qb   = b2b + NB2;
  bf16* kb   = qb + NX;
  bf16* vt   = kb + NX;
  bf16* aout = vt + NX;

  convert_inputs<<<dim3(1024), dim3(256), 0, stream>>>(
      x, Wqkv, bqkv, Wout, bout, xb, w1b, b1b, w2b, b2b, flagp);
  // QKV projection: M=4096, N=6144, K=2048 -> 768 blocks = 3 exact rounds
  gemmE<0><<<dim3(768), dim3(512), 0, stream>>>(
      xb, w1b, b1b, EMBED, (void*)qb, kb, vt, flagp);
  // attention: 32 bh * 16 balanced pairs
  attn_fwd<<<dim3(512), dim3(256), 0, stream>>>(qb, kb, vt, aout);
  // out projection: M=4096, N=2048, K=2048 -> 256 blocks = 1 exact round
  gemmE<1><<<dim3(256), dim3(512), 0, stream>>>(
      aout, w2b, b2b, EMBED, d_out, nullptr, nullptr, flagp);
}

// Round 5
// 388.687 us; speedup vs baseline: 1.1056x; 1.0162x over previous
//
#include <hip/hip_runtime.h>
#include <hip/hip_bf16.h>
#include <math.h>

#define SEQ   2048
#define EMBED 2048
#define NHEAD 16
#define DHEAD 128
#define BATCH 2

#define NX   ((size_t)BATCH * SEQ * EMBED)   // 8388608
#define NW1  ((size_t)3 * EMBED * EMBED)     // 12582912
#define NB1  ((size_t)3 * EMBED)             // 6144
#define NW2  ((size_t)EMBED * EMBED)         // 4194304
#define NB2  ((size_t)EMBED)                 // 2048

typedef __bf16 bf16;
typedef __attribute__((__ext_vector_type__(8))) __bf16 bf16x8;
typedef __attribute__((__ext_vector_type__(4))) __bf16 bf16x4;
typedef __attribute__((__ext_vector_type__(4))) float f32x4;
typedef __attribute__((__ext_vector_type__(4))) unsigned int u32x4;

#define NEG_BIG (-1.0e30f)

__device__ __forceinline__ f32x4 mfma_16x16x32(bf16x8 a, bf16x8 b, f32x4 c) {
  return __builtin_amdgcn_mfma_f32_16x16x32_bf16(a, b, c, 0, 0, 0);
}

// async global->LDS, 16B per lane; dst is wave-uniform base, lane i lands at
// dst + i*16B (m97-verified pattern)
__device__ __forceinline__ void llds16(bf16* dst, const bf16* src) {
  __builtin_amdgcn_global_load_lds(
      (const __attribute__((address_space(1))) void*)src,
      (__attribute__((address_space(3))) void*)dst, 16, 0, 0);
}

// raw barrier emitted as opaque asm: the compiler's memory legalizer cannot
// attach an s_waitcnt vmcnt(0) drain to it (T4 insurance). "memory" clobber
// still pins all LDS/global ops on either side.
#define BARRAW() asm volatile("s_barrier" ::: "memory")

// ---------------------------------------------------------------------------
// Input normalization: detect fp32 vs bf16 storage, convert to bf16 ws.
// ---------------------------------------------------------------------------
__global__ void convert_inputs(const void* __restrict__ xin,
                               const void* __restrict__ w1in,
                               const void* __restrict__ b1in,
                               const void* __restrict__ w2in,
                               const void* __restrict__ b2in,
                               bf16* __restrict__ xb, bf16* __restrict__ w1b,
                               bf16* __restrict__ b1b, bf16* __restrict__ w2b,
                               bf16* __restrict__ b2b, int* __restrict__ flagp)
{
  __shared__ int sflag;
  if (threadIdx.x == 0) sflag = 0;
  __syncthreads();
  const unsigned short* xh = (const unsigned short*)xin;
  int huge = 0;
  for (int i = threadIdx.x; i < 2048; i += 256) {
    float f = __uint_as_float((unsigned int)xh[i] << 16);
    if (!(fabsf(f) <= 1e4f)) huge = 1;  // catches NaN/Inf too
  }
  if (huge) sflag = 1;
  __syncthreads();
  const int isf32 = sflag;
  if (blockIdx.x == 0 && threadIdx.x == 0) *flagp = isf32;

  const void* srcs[5] = {xin, w1in, b1in, w2in, b2in};
  bf16* dsts[5] = {xb, w1b, b1b, w2b, b2b};
  const size_t lens[5] = {NX, NW1, NB1, NW2, NB2};
  const size_t gid = (size_t)blockIdx.x * blockDim.x + threadIdx.x;
  const size_t gstride = (size_t)gridDim.x * blockDim.x;
  for (int sidx = 0; sidx < 5; ++sidx) {
    const size_t n8 = lens[sidx] >> 3;
    bf16* d = dsts[sidx];
    if (isf32) {
      const float* s = (const float*)srcs[sidx];
      for (size_t i = gid; i < n8; i += gstride) {
        const float* sp = s + i * 8;
        bf16x8 r;
#pragma unroll
        for (int j = 0; j < 8; ++j) r[j] = (bf16)sp[j];
        *(bf16x8*)(d + i * 8) = r;
      }
    } else {
      const u32x4* s = (const u32x4*)srcs[sidx];
      for (size_t i = gid; i < n8; i += gstride)
        *(u32x4*)(d + i * 8) = s[i];
    }
  }
}

// ---------------------------------------------------------------------------
// QKV GEMM, 256x256 high-reuse pipeline: C = A[M,K]*B[N,K]^T + bias
// BM=BN=256, BK=64; 512 thr = 8 waves (2M x 4N), 128x64 out/wave.
// LDS 128KB: [buf2]{ A:[ks2][256][32] ; B:[ks2][256][32] } bf16, 64B rows,
// granule XOR (bit1 ^= row-bit3) on stage-source AND read (r4: 0 conflicts).
// Phase = one ks half of one K-tile: 12 ds_read_b128 (8 A + 4 B frags) ->
// 32 MFMA (B-frag reused across 8 A-frags: 42.7 FLOP/LDS-byte, vs 32 at
// 64x64/wave) -> ONE barrier. Lockstep: the per-phase barrier keeps all
// waves in the same phase-interval; stage at (tt,ks) targets buf^1 (tile
// tt+1) so stage/read regions are ALWAYS disjoint within a phase.
// Landing: per-wave 4 llds16/phase; vmcnt(4) before each barrier leaves only
// this phase's stage in flight => prior phase's stage (the half-tile read
// next) has landed for EVERY wave before barrier release (m201 guarantee).
// Tail: (NT-1,ks0) -> vmcnt(0); final phase no wait.
// Grid 384 blocks (1.5 rounds; per-block rate gain >> packing loss).
// ---------------------------------------------------------------------------
__global__ __launch_bounds__(512, 1) void gemmM(
    const bf16* __restrict__ A, const bf16* __restrict__ B,
    const bf16* __restrict__ bias,
    bf16* __restrict__ outq, bf16* __restrict__ outk, bf16* __restrict__ outv)
{
  __shared__ __align__(16) bf16 lds_[65536];  // 128 KiB
  const int t = threadIdx.x;
  const int lane = t & 63, w = t >> 6;
  const int wm = w >> 2, wn = w & 3;          // 2M x 4N waves, 128x64 each
  const int lr = lane & 15, lq = lane >> 4;
  // XCD-bijective swizzle: 384 % 8 == 0, chunks of 48; by fastest (16 values)
  // -> B-panels L2-resident per bx-run while A-strips stream.
  const int f = blockIdx.x;
  const int o = (f & 7) * 48 + (f >> 3);
  const int by = o & 15, bx = o >> 4;
  const int m0 = by << 8, n0 = bx << 8;
  const int K = EMBED;
  const int NT = K >> 6;                      // 32 K-tiles

  // staging map: per half-tile (kt,ks): A 256 rows & B 256 rows, 32 KB total
  // = 4 llds16/wave (2 A + 2 B). Call: 16 rows x 32 k; lane -> row lane>>2,
  // phys granule lane&3, source granule XOR'd by row-bit3 = (lane>>5)&1.
  const int sg8 = ((lane & 3) ^ (((lane >> 5) & 1) << 1)) << 3;
  const bf16* aS  = A + (size_t)(m0 + w * 32 + (lane >> 2)) * K + sg8;
  const bf16* aS2 = aS + (size_t)16 * K;
  const bf16* bS  = B + (size_t)(n0 + w * 32 + (lane >> 2)) * K + sg8;
  const bf16* bS2 = bS + (size_t)16 * K;
  const int dA = w * 1024;          // elem offset of wave's A call-0 region
  const int dB = 16384 + w * 1024;  // elem offset of wave's B call-0 region

#define STAGE_HALF(kt_, ks_)                                                 \
  {                                                                          \
    const int _bufb = ((kt_) & 1) * 32768 + (ks_) * 8192;                    \
    const int _kc = ((kt_) << 6) + (ks_) * 32;                               \
    llds16(lds_ + _bufb + dA, aS + _kc);                                     \
    llds16(lds_ + _bufb + dA + 512, aS2 + _kc);                              \
    llds16(lds_ + _bufb + dB, bS + _kc);                                     \
    llds16(lds_ + _bufb + dB + 512, bS2 + _kc);                              \
  }

  f32x4 acc[8][4];
#pragma unroll
  for (int i = 0; i < 8; ++i)
#pragma unroll
    for (int j = 0; j < 4; ++j) acc[i][j] = (f32x4){0.f, 0.f, 0.f, 0.f};

  // fragment reads: row stride 64B; granule XOR by row-bit3 (= lr>>3, since
  // all base rows are multiples of 16). Verified conflict-free in r4.
  const int rg8 = (lq ^ (((lr >> 3) & 1) << 1)) << 3;
  const int arow_ = (wm * 128 + lr) * 32 + rg8;          // + ai*512
  const int brow_ = 16384 + (wn * 64 + lr) * 32 + rg8;   // + ni*512

  // prologue: tile 0 both halves; drain; barrier
  STAGE_HALF(0, 0);
  STAGE_HALF(0, 1);
  asm volatile("s_waitcnt vmcnt(0)" ::: "memory");
  BARRAW();

  for (int tt = 0; tt < NT; ++tt) {
    const int bufb = (tt & 1) * 32768;
#pragma unroll
    for (int ks = 0; ks < 2; ++ks) {
      const int base = bufb + ks * 8192;
      bf16x8 af[8], bfv[4];
#pragma unroll
      for (int ai = 0; ai < 8; ++ai)
        af[ai] = *(const bf16x8*)(lds_ + base + arow_ + ai * 512);
#pragma unroll
      for (int ni = 0; ni < 4; ++ni)
        bfv[ni] = *(const bf16x8*)(lds_ + base + brow_ + ni * 512);
      if (tt + 1 < NT) STAGE_HALF(tt + 1, ks);
      __builtin_amdgcn_s_setprio(1);
#pragma unroll
      for (int ai = 0; ai < 8; ++ai)
#pragma unroll
        for (int ni = 0; ni < 4; ++ni)
          acc[ai][ni] = mfma_16x16x32(af[ai], bfv[ni], acc[ai][ni]);
      __builtin_amdgcn_s_setprio(0);
      if (tt + 1 < NT) {
        asm volatile("s_waitcnt vmcnt(4)" ::: "memory");
      } else if (ks == 0) {
        asm volatile("s_waitcnt vmcnt(0)" ::: "memory");
      }
      BARRAW();
    }
  }
#undef STAGE_HALF

  // epilogue: row(M) = wm*128 + ai*16 + lq*4 + reg, col(N) = wn*64 + ni*16+lr
  const int which = n0 >> 11;          // 0:q 1:k 2:v  (256 | 2048 alignment)
  const int bbid = m0 >> 11;
  const int s0 = m0 & 2047;
  if (which == 2) {
    // V transposed: [BH, Dh, S]; 4 regs = 4 consecutive s -> 8B store
#pragma unroll
    for (int ni = 0; ni < 4; ++ni) {
      const int ng = n0 + wn * 64 + ni * 16 + lr;
      const int h = (ng >> 7) & 15;
      const int d = ng & 127;
      const float bv = (float)bias[ng];
      bf16* rowp =
          outv + ((size_t)(bbid * NHEAD + h) * DHEAD + d) * SEQ + s0 + wm * 128;
#pragma unroll
      for (int ai = 0; ai < 8; ++ai) {
        bf16x4 pk;
#pragma unroll
        for (int reg = 0; reg < 4; ++reg)
          pk[reg] = (bf16)(acc[ai][ni][reg] + bv);
        *(bf16x4*)(rowp + ai * 16 + lq * 4) = pk;
      }
    }
  } else {
    bf16* dst = (which == 0) ? outq : outk;
#pragma unroll
    for (int ni = 0; ni < 4; ++ni) {
      const int ng = n0 + wn * 64 + ni * 16 + lr;
      const int h = (ng >> 7) & 15;
      const int d = ng & 127;
      const float bv = (float)bias[ng];
      bf16* hb = dst + (size_t)(bbid * NHEAD + h) * SEQ * DHEAD + d;
#pragma unroll
      for (int ai = 0; ai < 8; ++ai)
#pragma unroll
        for (int reg = 0; reg < 4; ++reg) {
          const int s = s0 + wm * 128 + ai * 16 + lq * 4 + reg;
          hb[(size_t)s * DHEAD] = (bf16)(acc[ai][ni][reg] + bv);
        }
    }
  }
}

// ---------------------------------------------------------------------------
// 4-phase pipelined NT GEMM (r4, proven): used for the out-projection.
// BM=128, BN=256, BK=64; 512 thr = 8 waves (2M x 4N), 64x64 out/wave.
// ---------------------------------------------------------------------------
template <int MODE>
__global__ __launch_bounds__(512, 1) void gemmE(
    const bf16* __restrict__ A, const bf16* __restrict__ B,
    const bf16* __restrict__ bias, int K,
    void* __restrict__ out0v, bf16* __restrict__ out1, bf16* __restrict__ out2,
    const int* __restrict__ flagp)
{
  __shared__ __align__(16) bf16 lds_[49152];  // 96 KiB
  constexpr int NTX = (MODE == 0) ? 24 : 8;   // N / 256
  const int t = threadIdx.x;
  const int lane = t & 63, w = t >> 6;
  const int wm = w >> 2, wn = w & 3;          // 2M x 4N waves
  const int lr = lane & 15, lq = lane >> 4;
  const int nwg = 32 * NTX;
  const int f = blockIdx.x;
  const int o = (f & 7) * (nwg >> 3) + (f >> 3);
  const int by = o & 31, bx = o >> 5;
  const int m0 = by << 7, n0 = bx << 8;
  const int NT = K >> 6;                      // 32 K-tiles
  const int NI = NT >> 1;                     // 16 iterations

  const int srow = t >> 2;
  const int sg8 = (((t & 3) ^ (((t >> 5) & 1) << 1))) << 3;

#define STAGE3(kt_, ks_)                                                     \
  {                                                                          \
    const int _kt = (kt_), _ks = (ks_);                                      \
    if (_kt < NT) {                                                          \
      const int _bb = (_kt & 1) * 24576;                                     \
      const int _kc = (_kt << 6) + _ks * 32;                                 \
      llds16(lds_ + _bb + _ks * 4096 + (w << 9),                             \
             A + (size_t)(m0 + srow) * K + _kc + sg8);                       \
      llds16(lds_ + _bb + 8192 + _ks * 8192 + (w << 9),                      \
             B + (size_t)(n0 + srow) * K + _kc + sg8);                       \
      llds16(lds_ + _bb + 8192 + _ks * 8192 + 4096 + (w << 9),               \
             B + (size_t)(n0 + 128 + srow) * K + _kc + sg8);                 \
    }                                                                        \
  }

  f32x4 acc[4][4];
#pragma unroll
  for (int i = 0; i < 4; ++i)
#pragma unroll
    for (int j = 0; j < 4; ++j) acc[i][j] = (f32x4){0.f, 0.f, 0.f, 0.f};

  const int rg8 = ((lq ^ (((lr >> 3) & 1) << 1))) << 3;
  const int arow = (wm * 64 + lr) * 32 + rg8;
  const int brow = (wn * 64 + lr) * 32 + rg8;

  STAGE3(0, 0);
  STAGE3(0, 1);
  STAGE3(1, 0);
  asm volatile("s_waitcnt vmcnt(6)" ::: "memory");
  BARRAW();

  for (int i = 0; i < NI; ++i) {
    const int k2 = i << 1;
#pragma unroll
    for (int p = 0; p < 4; ++p) {
      const int ks = p & 1;
      const int bufb = (p >> 1) * 24576;
      bf16x8 af[4], bfv[4];
      const int ab = bufb + ks * 4096 + arow;
      const int bb = bufb + 8192 + ks * 8192 + brow;
#pragma unroll
      for (int mi = 0; mi < 4; ++mi)
        af[mi] = *(const bf16x8*)(lds_ + ab + mi * 512);
#pragma unroll
      for (int ni = 0; ni < 4; ++ni)
        bfv[ni] = *(const bf16x8*)(lds_ + bb + ni * 512);
      if (p == 0)      STAGE3(k2 + 1, 1)
      else if (p == 1) STAGE3(k2 + 2, 0)
      else if (p == 2) STAGE3(k2 + 2, 1)
      else             STAGE3(k2 + 3, 0)
      BARRAW();
      __builtin_amdgcn_s_setprio(1);
#pragma unroll
      for (int mi = 0; mi < 4; ++mi)
#pragma unroll
        for (int ni = 0; ni < 4; ++ni)
          acc[mi][ni] = mfma_16x16x32(af[mi], bfv[ni], acc[mi][ni]);
      __builtin_amdgcn_s_setprio(0);
      if (i == 0 && p == 0) {
        asm volatile("s_waitcnt vmcnt(6)" ::: "memory");
      }
      if (p == 1) {
        if (i == NI - 1) { asm volatile("s_waitcnt vmcnt(0)" ::: "memory"); }
        else             { asm volatile("s_waitcnt vmcnt(3)" ::: "memory"); }
      }
      if (p == 3 && i < NI - 1) {
        asm volatile("s_waitcnt vmcnt(3)" ::: "memory");
      }
      BARRAW();
    }
  }
#undef STAGE3

  if (MODE == 0) {
    const int which = n0 >> 11;
    const int bbid = m0 >> 11;
    const int s0 = m0 & 2047;
    if (which == 2) {
      bf16* dst = out2;
#pragma unroll
      for (int ni = 0; ni < 4; ++ni) {
        const int ng = n0 + wn * 64 + ni * 16 + lr;
        const int h = (ng >> 7) & 15;
        const int d = ng & 127;
        const float bv = (float)bias[ng];
        bf16* rowp =
            dst + ((size_t)(bbid * NHEAD + h) * DHEAD + d) * SEQ + s0 + wm * 64;
#pragma unroll
        for (int mi = 0; mi < 4; ++mi) {
          bf16x4 pk;
#pragma unroll
          for (int reg = 0; reg < 4; ++reg)
            pk[reg] = (bf16)(acc[mi][ni][reg] + bv);
          *(bf16x4*)(rowp + mi * 16 + lq * 4) = pk;
        }
      }
    } else {
      bf16* dst = (which == 0) ? (bf16*)out0v : out1;
#pragma unroll
      for (int ni = 0; ni < 4; ++ni) {
        const int ng = n0 + wn * 64 + ni * 16 + lr;
        const int h = (ng >> 7) & 15;
        const int d = ng & 127;
        const float bv = (float)bias[ng];
        bf16* hb = dst + (size_t)(bbid * NHEAD + h) * SEQ * DHEAD + d;
#pragma unroll
        for (int mi = 0; mi < 4; ++mi)
#pragma unroll
          for (int reg = 0; reg < 4; ++reg) {
            const int s = s0 + wm * 64 + mi * 16 + lq * 4 + reg;
            hb[(size_t)s * DHEAD] = (bf16)(acc[mi][ni][reg] + bv);
          }
      }
    }
  } else {
    const int isf32 = *flagp;
#pragma unroll
    for (int ni = 0; ni < 4; ++ni) {
      const int col = n0 + wn * 64 + ni * 16 + lr;
      const float bv = (float)bias[col];
#pragma unroll
      for (int mi = 0; mi < 4; ++mi)
#pragma unroll
        for (int reg = 0; reg < 4; ++reg) {
          const int row = m0 + wm * 64 + mi * 16 + lq * 4 + reg;
          const float v = acc[mi][ni][reg] + bv;
          const size_t idx = (size_t)row * EMBED + col;
          if (isf32) ((float*)out0v)[idx] = v;
          else       ((bf16*)out0v)[idx] = (bf16)v;
        }
    }
  }
}

// ---------------------------------------------------------------------------
// Causal flash attention, pair-balanced: block (bh, p) handles q-tiles
// {p, 31-p} (64 rows each) over the shared K range kt=0..31-p.
// Swapped-operand form: S^T = mfma(K,Q); lane owns one q-row; P via
// XOR-swizzled packed ds_write_b64; PV computes O^T = V^T * P^T.
// ---------------------------------------------------------------------------
__device__ __forceinline__ void qk_softmax_tile(
    const bf16* __restrict__ sK, bf16* __restrict__ sP, const bf16x8* aq,
    float& m_i, float& l_i, f32x4* oacc, int kt, int qt,
    int w, int lr, int lq, int sPofs)
{
  const float scale = 0.08838834764831845f;  // 1/sqrt(128)
  f32x4 tacc[4];
#pragma unroll
  for (int ni = 0; ni < 4; ++ni) tacc[ni] = (f32x4){0.f, 0.f, 0.f, 0.f};
#pragma unroll
  for (int ks = 0; ks < 4; ++ks)
#pragma unroll
    for (int ni = 0; ni < 4; ++ni) {
      bf16x8 bk = *(const bf16x8*)(sK + (ni * 16 + lr) * 136 + ks * 32 + lq * 8);
      tacc[ni] = mfma_16x16x32(bk, aq[ks], tacc[ni]);
    }
  float pp[4][4];
  const int qg = qt * 64 + w * 16 + lr;
#pragma unroll
  for (int ni = 0; ni < 4; ++ni)
#pragma unroll
    for (int reg = 0; reg < 4; ++reg) {
      float sv = tacc[ni][reg] * scale;
      if (kt == qt) {
        const int kg = kt * 64 + ni * 16 + lq * 4 + reg;
        if (kg > qg) sv = NEG_BIG;
      }
      pp[ni][reg] = sv;
    }
  float mx;
  {
    float a0 = fmaxf(fmaxf(pp[0][0], pp[0][1]), fmaxf(pp[0][2], pp[0][3]));
    float a1 = fmaxf(fmaxf(pp[1][0], pp[1][1]), fmaxf(pp[1][2], pp[1][3]));
    float a2 = fmaxf(fmaxf(pp[2][0], pp[2][1]), fmaxf(pp[2][2], pp[2][3]));
    float a3 = fmaxf(fmaxf(pp[3][0], pp[3][1]), fmaxf(pp[3][2], pp[3][3]));
    mx = fmaxf(fmaxf(a0, a1), fmaxf(a2, a3));
  }
  mx = fmaxf(mx, __shfl_xor(mx, 16, 64));
  mx = fmaxf(mx, __shfl_xor(mx, 32, 64));
  const float mnew = fmaxf(m_i, mx);
  const float alpha = __expf(m_i - mnew);
  float ls = 0.f;
#pragma unroll
  for (int ni = 0; ni < 4; ++ni) {
    float s0 = __expf(pp[ni][0] - mnew);
    float s1 = __expf(pp[ni][1] - mnew);
    float s2 = __expf(pp[ni][2] - mnew);
    float s3 = __expf(pp[ni][3] - mnew);
    pp[ni][0] = s0; pp[ni][1] = s1; pp[ni][2] = s2; pp[ni][3] = s3;
    ls += (s0 + s1) + (s2 + s3);
  }
  ls += __shfl_xor(ls, 16, 64);
  ls += __shfl_xor(ls, 32, 64);
  l_i = l_i * alpha + ls;
  m_i = mnew;
#pragma unroll
  for (int dt = 0; dt < 8; ++dt) oacc[dt] *= alpha;
  bf16* rowp = sP + (sPofs + w * 16 + lr) * 64;
  const int swz = lr & 7;
#pragma unroll
  for (int ni = 0; ni < 4; ++ni) {
    bf16x4 pk;
#pragma unroll
    for (int reg = 0; reg < 4; ++reg) pk[reg] = (bf16)pp[ni][reg];
    const int col = ni * 16 + lq * 4;
    const int scol = (((col >> 3) ^ swz) << 3) | (col & 7);
    *(bf16x4*)(rowp + scol) = pk;
  }
}

__device__ __forceinline__ void pv_tile(const bf16* __restrict__ sP,
                                        const bf16* __restrict__ sV,
                                        f32x4* oacc, int w, int lr, int lq,
                                        int sPofs)
{
  const bf16* rowp = sP + (sPofs + w * 16 + lr) * 64;
  const int swz = lr & 7;
#pragma unroll
  for (int ks2 = 0; ks2 < 2; ++ks2) {
    const int chunk = ks2 * 4 + lq;
    bf16x8 bp = *(const bf16x8*)(rowp + ((chunk ^ swz) << 3));
#pragma unroll
    for (int dt = 0; dt < 8; ++dt) {
      bf16x8 av =
          *(const bf16x8*)(sV + (dt * 16 + lr) * 72 + ks2 * 32 + lq * 8);
      oacc[dt] = mfma_16x16x32(av, bp, oacc[dt]);
    }
  }
}

__global__ __launch_bounds__(256, 2) void attn_fwd(
    const bf16* __restrict__ qb, const bf16* __restrict__ kb,
    const bf16* __restrict__ vt, bf16* __restrict__ aout)
{
  __shared__ bf16 sK[64 * 136];    // [k][d], +8 pad
  __shared__ bf16 sV[128 * 72];    // [d][k], +8 pad
  __shared__ bf16 sP[128 * 64];    // [q][k] XOR-swizzled
  const int t = threadIdx.x;
  const int lane = t & 63, w = t >> 6;
  const int lr = lane & 15, lq = lane >> 4;
  const int p  = blockIdx.x & 15;
  const int bh = blockIdx.x >> 4;
  const int bb = bh >> 4, h = bh & 15;
  const int qlo = p, qhi = 31 - p;

  bf16x8 aqL[4], aqH[4];
  {
    const bf16* qpL =
        qb + ((size_t)bh * SEQ + qlo * 64 + w * 16 + lr) * DHEAD + lq * 8;
    const bf16* qpH =
        qb + ((size_t)bh * SEQ + qhi * 64 + w * 16 + lr) * DHEAD + lq * 8;
#pragma unroll
    for (int ks = 0; ks < 4; ++ks) {
      aqL[ks] = *(const bf16x8*)(qpL + ks * 32);
      aqH[ks] = *(const bf16x8*)(qpH + ks * 32);
    }
  }

  f32x4 oL[8], oH[8];
#pragma unroll
  for (int i = 0; i < 8; ++i) {
    oL[i] = (f32x4){0.f, 0.f, 0.f, 0.f};
    oH[i] = (f32x4){0.f, 0.f, 0.f, 0.f};
  }
  float mL = NEG_BIG, mH = NEG_BIG;
  float lL = 0.f, lH = 0.f;

  bf16x8 rk[4], rv[4];
  const int kr_ = t >> 4, kd_ = t & 15;
  const int vr_ = t >> 3, vk_ = t & 7;
#define FETCH(ktv)                                                          \
  {                                                                         \
    const int _kt = (ktv);                                                  \
    _Pragma("unroll") for (int i = 0; i < 4; ++i) {                         \
      rk[i] = *(const bf16x8*)(kb + ((size_t)bh * SEQ + _kt * 64 +          \
                                     (i * 16 + kr_)) * DHEAD + kd_ * 8);    \
      rv[i] = *(const bf16x8*)(vt + ((size_t)bh * DHEAD + (i * 32 + vr_)) * \
                                     SEQ + _kt * 64 + vk_ * 8);             \
    }                                                                       \
  }
#define COMMIT()                                                            \
  {                                                                         \
    _Pragma("unroll") for (int i = 0; i < 4; ++i) {                         \
      *(bf16x8*)(sK + (i * 16 + kr_) * 136 + kd_ * 8) = rk[i];              \
      *(bf16x8*)(sV + (i * 32 + vr_) * 72 + vk_ * 8) = rv[i];               \
    }                                                                       \
  }

  FETCH(0);
  COMMIT();
  __syncthreads();

  for (int kt = 0; kt <= qhi; ++kt) {
    if (kt < qhi) FETCH(kt + 1);
    const bool doLo = (kt <= qlo);

    qk_softmax_tile(sK, sP, aqH, mH, lH, oH, kt, qhi, w, lr, lq, 64);
    if (doLo) qk_softmax_tile(sK, sP, aqL, mL, lL, oL, kt, qlo, w, lr, lq, 0);
    asm volatile("s_waitcnt lgkmcnt(0)" ::: "memory");
    pv_tile(sP, sV, oH, w, lr, lq, 64);
    if (doLo) pv_tile(sP, sV, oL, w, lr, lq, 0);

    __syncthreads();
    if (kt < qhi) {
      COMMIT();
      __syncthreads();
    }
  }

#pragma unroll
  for (int side = 0; side < 2; ++side) {
    const f32x4* oacc = side ? oH : oL;
    const float linv = 1.0f / (side ? lH : lL);
    const int qt = side ? qhi : qlo;
    const int qg = qt * 64 + w * 16 + lr;
    bf16* outp = aout + ((size_t)bb * SEQ + qg) * EMBED + h * 128 + lq * 4;
#pragma unroll
    for (int dt = 0; dt < 8; ++dt) {
      bf16x4 pk;
#pragma unroll
      for (int reg = 0; reg < 4; ++reg)
        pk[reg] = (bf16)(oacc[dt][reg] * linv);
      *(bf16x4*)(outp + dt * 16) = pk;
    }
  }
#undef FETCH
#undef COMMIT
}

extern "C" void kernel_launch(void* const* d_in, const int* in_sizes, int n_in,
                              void* d_out, int out_size, void* d_ws, size_t ws_size,
                              hipStream_t stream) {
  const void* x    = d_in[0];
  const void* Wqkv = d_in[1];
  const void* bqkv = d_in[2];
  const void* Wout = d_in[3];
  const void* bout = d_in[4];

  int* flagp = (int*)d_ws;
  bf16* base = (bf16*)((char*)d_ws + 256);
  bf16* xb   = base;
  bf16* w1b  = xb + NX;
  bf16* b1b  = w1b + NW1;
  bf16* w2b  = b1b + NB1;
  bf16* b2b  = w2b + NW2;
  bf16* qb   = b2b + NB2;
  bf16* kb   = qb + NX;
  bf16* vt   = kb + NX;
  bf16* aout = vt + NX;

  convert_inputs<<<dim3(1024), dim3(256), 0, stream>>>(
      x, Wqkv, bqkv, Wout, bout, xb, w1b, b1b, w2b, b2b, flagp);
  // QKV projection: M=4096, N=6144, K=2048 -> 384 blocks of 256x256
  gemmM<<<dim3(384), dim3(512), 0, stream>>>(xb, w1b, b1b, qb, kb, vt);
  // attention: 32 bh * 16 balanced pairs
  attn_fwd<<<dim3(512), dim3(256), 0, stream>>>(qb, kb, vt, aout);
  // out projection: M=4096, N=2048, K=2048 -> 256 blocks = 1 exact round
  gemmE<1><<<dim3(256), dim3(512), 0, stream>>>(
      aout, w2b, b2b, EMBED, d_out, nullptr, nullptr, flagp);
}